// Round 9
// baseline (553.445 us; speedup 1.0000x reference)
//
#include <hip/hip_runtime.h>
#include <hip/hip_bf16.h>

#define D 128            // D_IN == D_OUT
#define NSLICE 8         // 8 col-slices of 16 cols (32 B bf16 per row-slice)

typedef __attribute__((ext_vector_type(8))) short  short8;
typedef __attribute__((ext_vector_type(4))) float  f32x4;
typedef __attribute__((ext_vector_type(2))) float  f32x2;

// fp32 -> bf16 (RTNE)
__device__ __forceinline__ unsigned f2bf(float f) {
    unsigned u = __float_as_uint(f);
    u += 0x7FFFu + ((u >> 16) & 1u);
    return u >> 16;
}
__device__ __forceinline__ unsigned pk2(float a, float b) {
    return f2bf(a) | (f2bf(b) << 16);
}
__device__ __forceinline__ float bflo(unsigned u) { return __uint_as_float(u << 16); }
__device__ __forceinline__ float bfhi(unsigned u) { return __uint_as_float(u & 0xFFFF0000u); }

// ---------------------------------------------------------------------------
// Kernel 1: y = bf16(x @ W) via MFMA 16x16x32 bf16, slice-major store
// y[slice][node][16 cols].  (unchanged from R8 — correctness-proven)
// ---------------------------------------------------------------------------
__global__ __launch_bounds__(256, 2) void gemm_mfma_kernel(
    const float* __restrict__ x, const float* __restrict__ W,
    unsigned* __restrict__ y, int n_nodes, int ntiles)
{
    __shared__ unsigned short Wt[D * D];   // bf16 [c][k], k XOR-swizzled, 32 KB

    const int t = threadIdx.x;
    const size_t NN = (size_t)n_nodes;

    {
        const float4* W4 = reinterpret_cast<const float4*>(W);
#pragma unroll
        for (int m = 0; m < 16; ++m) {
            const int idx4 = m * 256 + t;        // float4 index
            const int k  = idx4 >> 5;            // 32 float4 per k-row
            const int c0 = (idx4 & 31) << 2;
            const float4 w = W4[idx4];
            const float wv[4] = {w.x, w.y, w.z, w.w};
#pragma unroll
            for (int i = 0; i < 4; ++i) {
                const int c    = c0 + i;
                const int slot = (k >> 3) ^ (c & 15);
                Wt[c * 128 + slot * 8 + (k & 7)] = (unsigned short)f2bf(wv[i]);
            }
        }
    }
    __syncthreads();

    const int lane = t & 63;
    const int cl   = lane & 15;
    const int g    = lane >> 4;

    short8 wf[8][4];
#pragma unroll
    for (int ct = 0; ct < 8; ++ct)
#pragma unroll
        for (int ks = 0; ks < 4; ++ks) {
            const int c    = ct * 16 + cl;
            const int slot = (ks * 4 + g) ^ cl;
            wf[ct][ks] = *reinterpret_cast<const short8*>(&Wt[c * 128 + slot * 8]);
        }

    const int wave   = (blockIdx.x << 2) | (t >> 6);
    const int nwaves = gridDim.x << 2;

#define LOADX(rt_, buf_)                                                      \
    {                                                                         \
        int r_ = (rt_) * 16 + cl;                                             \
        if (r_ >= n_nodes) r_ = n_nodes - 1;                                  \
        const float* p_ = x + (size_t)r_ * D + g * 8;                         \
        _Pragma("unroll")                                                     \
        for (int ks_ = 0; ks_ < 4; ++ks_) {                                   \
            buf_[2 * ks_]     = *reinterpret_cast<const float4*>(p_ + ks_ * 32);     \
            buf_[2 * ks_ + 1] = *reinterpret_cast<const float4*>(p_ + ks_ * 32 + 4); \
        }                                                                     \
    }

#define COMPUTE(rt_, buf_)                                                    \
    {                                                                         \
        f32x4 acc_[8];                                                        \
        _Pragma("unroll")                                                     \
        for (int ct_ = 0; ct_ < 8; ++ct_) acc_[ct_] = (f32x4)(0.f);           \
        _Pragma("unroll")                                                     \
        for (int ks_ = 0; ks_ < 4; ++ks_) {                                   \
            short8 xf_;                                                       \
            unsigned* xu_ = reinterpret_cast<unsigned*>(&xf_);                \
            const float4 a_ = buf_[2 * ks_], b_ = buf_[2 * ks_ + 1];          \
            xu_[0] = pk2(a_.x, a_.y); xu_[1] = pk2(a_.z, a_.w);               \
            xu_[2] = pk2(b_.x, b_.y); xu_[3] = pk2(b_.z, b_.w);               \
            _Pragma("unroll")                                                 \
            for (int ct_ = 0; ct_ < 8; ++ct_)                                 \
                acc_[ct_] = __builtin_amdgcn_mfma_f32_16x16x32_bf16(          \
                    wf[ct_][ks_], xf_, acc_[ct_], 0, 0, 0);                   \
        }                                                                     \
        const int r_ = (rt_) * 16 + cl;                                       \
        if (r_ < n_nodes) {                                                   \
            _Pragma("unroll")                                                 \
            for (int ct_ = 0; ct_ < 8; ++ct_) {                               \
                uint2 v2_ = make_uint2(pk2(acc_[ct_][0], acc_[ct_][1]),       \
                                       pk2(acc_[ct_][2], acc_[ct_][3]));      \
                unsigned* yp_ = y + ((size_t)ct_ * NN + r_) * 8 + g * 2;      \
                *reinterpret_cast<uint2*>(yp_) = v2_;                         \
            }                                                                 \
        }                                                                     \
    }

    int rt = wave;
    if (rt >= ntiles) return;
    float4 bufA[8], bufB[8];
    LOADX(rt, bufA);
    while (true) {
        int nxt = rt + nwaves;
        if (nxt < ntiles) {
            LOADX(nxt, bufB);
            COMPUTE(rt, bufA);
            rt = nxt;
            nxt = rt + nwaves;
            if (nxt < ntiles) {
                LOADX(nxt, bufA);
                COMPUTE(rt, bufB);
                rt = nxt;
            } else { COMPUTE(rt, bufB); break; }
        } else { COMPUTE(rt, bufA); break; }
    }
#undef LOADX
#undef COMPUTE
}

// ---------------------------------------------------------------------------
// Kernel 2: build CSR row_ptr from sorted edge_row.
// ---------------------------------------------------------------------------
__global__ __launch_bounds__(256) void build_rowptr_kernel(
    const int* __restrict__ row, int* __restrict__ ptr, int n_edges, int n_nodes)
{
    int e = blockIdx.x * blockDim.x + threadIdx.x;
    if (e > n_edges) return;
    int lo, hi;                     // set ptr[r] = e for r in (lo, hi]
    if (e == 0)            { lo = -1;               hi = row[0];   }
    else if (e == n_edges) { lo = row[n_edges - 1]; hi = n_nodes;  }
    else {
        lo = row[e - 1];
        hi = row[e];
        if (lo == hi) return;
    }
    for (int r = lo + 1; r <= hi; ++r) ptr[r] = e;
}

// ---------------------------------------------------------------------------
// Kernel 2b: zero the 8 per-slice work-queue counters.
// ---------------------------------------------------------------------------
__global__ void zero_queue_kernel(int* __restrict__ q) {
    if (threadIdx.x < NSLICE) q[threadIdx.x] = 0;
}

// ---------------------------------------------------------------------------
// Kernel 3: XCD-pinned col-sliced SpMM with per-slice atomic work queues.
// Each block reads its REAL XCD id (s_getreg HW_REG_XCC_ID) and claims
// row-blocks of ITS slice from queue[xcd] -> slice (3.2 MB) stays resident
// in that XCD's 4 MiB L2. After own queue drains, steal from other slices
// (correctness even if XCC_ID were degenerate). Wave = 8 rows x 8 lanes;
// lane owns dword d (2 cols). 4-edge batches, double-buffered cv+gathers
// (R7-proven PHASE pipeline), vals pre-masked.
// ---------------------------------------------------------------------------
__global__ __launch_bounds__(256, 8) void spmm_sliced_kernel(
    const unsigned* __restrict__ ys,     // [NSLICE][n_nodes][8] dwords
    const int* __restrict__ ptr,
    const int* __restrict__ col, const float* __restrict__ val,
    float* __restrict__ out, int* __restrict__ queue,
    int n_nodes, int n_edges, int rblocks)
{
    unsigned xcd;
    asm volatile("s_getreg_b32 %0, hwreg(HW_REG_XCC_ID)" : "=s"(xcd));
    xcd &= (NSLICE - 1);

    const int w    = threadIdx.x >> 6;   // wave 0..3
    const int lane = threadIdx.x & 63;
    const int rl   = lane >> 3;          // row within wave's 8
    const int d    = lane & 7;           // dword within 32 B slice

    __shared__ int s_idx;

#define CVLOAD(b_, C_, V_)                                                   \
    {                                                                        \
        const int o_ = base + ((b_) << 2);                                   \
        if (o_ + 4 <= n_edges) {                                             \
            C_ = *reinterpret_cast<const int4*>(col + o_);                   \
            V_ = *reinterpret_cast<const float4*>(val + o_);                 \
        } else {                                                             \
            const int m_ = n_edges - 1;                                      \
            C_.x = col[min(o_ + 0, m_)]; C_.y = col[min(o_ + 1, m_)];        \
            C_.z = col[min(o_ + 2, m_)]; C_.w = col[min(o_ + 3, m_)];        \
            V_.x = val[min(o_ + 0, m_)]; V_.y = val[min(o_ + 1, m_)];        \
            V_.z = val[min(o_ + 2, m_)]; V_.w = val[min(o_ + 3, m_)];        \
        }                                                                    \
        V_.x = (o_ + 0 >= s && o_ + 0 < e) ? V_.x : 0.f;                     \
        V_.y = (o_ + 1 >= s && o_ + 1 < e) ? V_.y : 0.f;                     \
        V_.z = (o_ + 2 >= s && o_ + 2 < e) ? V_.z : 0.f;                     \
        V_.w = (o_ + 3 >= s && o_ + 3 < e) ? V_.w : 0.f;                     \
    }
#define GATHER(C_, U_)                                                       \
    {                                                                        \
        U_[0] = ybase[(size_t)C_.x << 3];                                    \
        U_[1] = ybase[(size_t)C_.y << 3];                                    \
        U_[2] = ybase[(size_t)C_.z << 3];                                    \
        U_[3] = ybase[(size_t)C_.w << 3];                                    \
    }
#define CONSUME(U_, V_)                                                      \
    {                                                                        \
        f32x2 t_, vv_;                                                       \
        t_.x = bflo(U_[0]); t_.y = bfhi(U_[0]);                              \
        vv_.x = V_.x; vv_.y = V_.x; acc += vv_ * t_;                         \
        t_.x = bflo(U_[1]); t_.y = bfhi(U_[1]);                              \
        vv_.x = V_.y; vv_.y = V_.y; acc += vv_ * t_;                         \
        t_.x = bflo(U_[2]); t_.y = bfhi(U_[2]);                              \
        vv_.x = V_.z; vv_.y = V_.z; acc += vv_ * t_;                         \
        t_.x = bflo(U_[3]); t_.y = bfhi(U_[3]);                              \
        vv_.x = V_.w; vv_.y = V_.w; acc += vv_ * t_;                         \
    }

    for (int sl = 0; sl < NSLICE; ++sl) {
        const int slice = (xcd + sl) & (NSLICE - 1);
        const unsigned* ybase = ys + (size_t)slice * n_nodes * 8 + d;

        for (;;) {
            if (threadIdx.x == 0) s_idx = atomicAdd(queue + slice, 1);
            __syncthreads();
            const int rblk = s_idx;
            __syncthreads();
            if (rblk >= rblocks) break;

            const int row = (rblk << 5) + (w << 3) + rl;
            if (row < n_nodes) {
                const int s = ptr[row];
                const int e = ptr[row + 1];
                const int base = s & ~3;
                const int nb = (e - base + 3) >> 2;

                f32x2 acc; acc.x = 0.f; acc.y = 0.f;
                int4   C0, C1;
                float4 V0, V1;
                unsigned U[4], T[4];

                if (nb > 0) {
                    CVLOAD(0, C0, V0);
                    GATHER(C0, U);
                    if (nb > 1) CVLOAD(1, C1, V1);
                    int b = 0;
                    while (true) {
                        if (b + 1 < nb) GATHER(C1, T);
                        CONSUME(U, V0);
                        if (b + 2 < nb) CVLOAD(b + 2, C0, V0);
                        if (++b >= nb) break;
                        if (b + 1 < nb) GATHER(C0, U);
                        CONSUME(T, V1);
                        if (b + 2 < nb) CVLOAD(b + 2, C1, V1);
                        if (++b >= nb) break;
                    }
                }

                float* op = out + (size_t)row * D + slice * 16 + d * 2;
                __builtin_nontemporal_store(acc, reinterpret_cast<f32x2*>(op));
            }
        }
    }
#undef CVLOAD
#undef GATHER
#undef CONSUME
}

// ---------------------------------------------------------------------------
extern "C" void kernel_launch(void* const* d_in, const int* in_sizes, int n_in,
                              void* d_out, int out_size, void* d_ws, size_t ws_size,
                              hipStream_t stream)
{
    const float* x        = (const float*)d_in[0];
    const int*   edge_row = (const int*)  d_in[1];
    const int*   edge_col = (const int*)  d_in[2];
    const float* edge_val = (const float*)d_in[3];
    const float* W        = (const float*)d_in[4];
    float*       out      = (float*)d_out;

    const int n_nodes = in_sizes[0] / D;
    const int n_edges = in_sizes[1];
    const int ntiles  = (n_nodes + 15) / 16;
    const int rblocks = (n_nodes + 31) / 32;

    // ws layout: y slice-major [8][n_nodes][16] bf16 (= n_nodes*256 B)
    //          | row_ptr (n_nodes+1) i32 | queue 8 i32
    unsigned* y     = (unsigned*)d_ws;
    int*      ptr   = (int*)((char*)d_ws + (size_t)n_nodes * 256);
    int*      queue = ptr + (n_nodes + 1);

    // 0) zero work queues
    zero_queue_kernel<<<1, 64, 0, stream>>>(queue);

    // 1) y = bf16(x @ W)  (MFMA, slice-major store)
    gemm_mfma_kernel<<<512, 256, 0, stream>>>(x, W, y, n_nodes, ntiles);

    // 2) row_ptr
    {
        int blocks = (n_edges + 1 + 255) / 256;
        build_rowptr_kernel<<<blocks, 256, 0, stream>>>(edge_row, ptr, n_edges, n_nodes);
    }
    // 3) out = A @ y   (XCD-pinned sliced, work-queue)
    spmm_sliced_kernel<<<2048, 256, 0, stream>>>((const unsigned*)y, ptr,
                                                 edge_col, edge_val,
                                                 out, queue,
                                                 n_nodes, n_edges, rblocks);
}

// Round 10
// 163.138 us; speedup vs baseline: 3.3925x; 3.3925x over previous
//
#include <hip/hip_runtime.h>
#include <hip/hip_bf16.h>

#define D 128            // D_IN == D_OUT
#define D2U 64           // D/2 packed bf16 pairs (uint) per row

typedef __attribute__((ext_vector_type(8))) short  short8;
typedef __attribute__((ext_vector_type(4))) float  f32x4;
typedef __attribute__((ext_vector_type(2))) float  f32x2;

// fp32 -> bf16 (RTNE)
__device__ __forceinline__ unsigned f2bf(float f) {
    unsigned u = __float_as_uint(f);
    u += 0x7FFFu + ((u >> 16) & 1u);
    return u >> 16;
}
__device__ __forceinline__ unsigned pk2(float a, float b) {
    return f2bf(a) | (f2bf(b) << 16);
}
__device__ __forceinline__ float bflo(unsigned u) { return __uint_as_float(u << 16); }
__device__ __forceinline__ float bfhi(unsigned u) { return __uint_as_float(u & 0xFFFF0000u); }

// ---------------------------------------------------------------------------
// Kernel 1: y = bf16(x @ W) via MFMA 16x16x32 bf16, ROW-MAJOR y (R6 version).
// ---------------------------------------------------------------------------
__global__ __launch_bounds__(256, 2) void gemm_mfma_kernel(
    const float* __restrict__ x, const float* __restrict__ W,
    unsigned* __restrict__ y, int n_nodes, int ntiles)
{
    __shared__ unsigned short Wt[D * D];   // bf16 [c][k], k XOR-swizzled, 32 KB

    const int t = threadIdx.x;

    {
        const float4* W4 = reinterpret_cast<const float4*>(W);
#pragma unroll
        for (int m = 0; m < 16; ++m) {
            const int idx4 = m * 256 + t;        // float4 index
            const int k  = idx4 >> 5;            // 32 float4 per k-row
            const int c0 = (idx4 & 31) << 2;
            const float4 w = W4[idx4];
            const float wv[4] = {w.x, w.y, w.z, w.w};
#pragma unroll
            for (int i = 0; i < 4; ++i) {
                const int c    = c0 + i;
                const int slot = (k >> 3) ^ (c & 15);
                Wt[c * 128 + slot * 8 + (k & 7)] = (unsigned short)f2bf(wv[i]);
            }
        }
    }
    __syncthreads();

    const int lane = t & 63;
    const int cl   = lane & 15;
    const int g    = lane >> 4;

    short8 wf[8][4];
#pragma unroll
    for (int ct = 0; ct < 8; ++ct)
#pragma unroll
        for (int ks = 0; ks < 4; ++ks) {
            const int c    = ct * 16 + cl;
            const int slot = (ks * 4 + g) ^ cl;
            wf[ct][ks] = *reinterpret_cast<const short8*>(&Wt[c * 128 + slot * 8]);
        }

    const int wave   = (blockIdx.x << 2) | (t >> 6);
    const int nwaves = gridDim.x << 2;

#define LOADX(rt_, buf_)                                                      \
    {                                                                         \
        int r_ = (rt_) * 16 + cl;                                             \
        if (r_ >= n_nodes) r_ = n_nodes - 1;                                  \
        const float* p_ = x + (size_t)r_ * D + g * 8;                         \
        _Pragma("unroll")                                                     \
        for (int ks_ = 0; ks_ < 4; ++ks_) {                                   \
            buf_[2 * ks_]     = *reinterpret_cast<const float4*>(p_ + ks_ * 32);     \
            buf_[2 * ks_ + 1] = *reinterpret_cast<const float4*>(p_ + ks_ * 32 + 4); \
        }                                                                     \
    }

#define COMPUTE(rt_, buf_)                                                    \
    {                                                                         \
        f32x4 acc_[8];                                                        \
        _Pragma("unroll")                                                     \
        for (int ct_ = 0; ct_ < 8; ++ct_) acc_[ct_] = (f32x4)(0.f);           \
        _Pragma("unroll")                                                     \
        for (int ks_ = 0; ks_ < 4; ++ks_) {                                   \
            short8 xf_;                                                       \
            unsigned* xu_ = reinterpret_cast<unsigned*>(&xf_);                \
            const float4 a_ = buf_[2 * ks_], b_ = buf_[2 * ks_ + 1];          \
            xu_[0] = pk2(a_.x, a_.y); xu_[1] = pk2(a_.z, a_.w);               \
            xu_[2] = pk2(b_.x, b_.y); xu_[3] = pk2(b_.z, b_.w);               \
            _Pragma("unroll")                                                 \
            for (int ct_ = 0; ct_ < 8; ++ct_)                                 \
                acc_[ct_] = __builtin_amdgcn_mfma_f32_16x16x32_bf16(          \
                    wf[ct_][ks_], xf_, acc_[ct_], 0, 0, 0);                   \
        }                                                                     \
        const int r_ = (rt_) * 16 + cl;                                       \
        if (r_ < n_nodes) {                                                   \
            unsigned* yp_ = y + (size_t)r_ * D2U + g * 2;                     \
            _Pragma("unroll")                                                 \
            for (int ct_ = 0; ct_ < 8; ++ct_) {                               \
                uint2 v2_ = make_uint2(pk2(acc_[ct_][0], acc_[ct_][1]),       \
                                       pk2(acc_[ct_][2], acc_[ct_][3]));      \
                *reinterpret_cast<uint2*>(yp_ + ct_ * 8) = v2_;               \
            }                                                                 \
        }                                                                     \
    }

    int rt = wave;
    if (rt >= ntiles) return;
    float4 bufA[8], bufB[8];
    LOADX(rt, bufA);
    while (true) {
        int nxt = rt + nwaves;
        if (nxt < ntiles) {
            LOADX(nxt, bufB);
            COMPUTE(rt, bufA);
            rt = nxt;
            nxt = rt + nwaves;
            if (nxt < ntiles) {
                LOADX(nxt, bufA);
                COMPUTE(rt, bufB);
                rt = nxt;
            } else { COMPUTE(rt, bufB); break; }
        } else { COMPUTE(rt, bufA); break; }
    }
#undef LOADX
#undef COMPUTE
}

// ---------------------------------------------------------------------------
// Kernel 2: build CSR row_ptr from sorted edge_row.
// ---------------------------------------------------------------------------
__global__ __launch_bounds__(256) void build_rowptr_kernel(
    const int* __restrict__ row, int* __restrict__ ptr, int n_edges, int n_nodes)
{
    int e = blockIdx.x * blockDim.x + threadIdx.x;
    if (e > n_edges) return;
    int lo, hi;                     // set ptr[r] = e for r in (lo, hi]
    if (e == 0)            { lo = -1;               hi = row[0];   }
    else if (e == n_edges) { lo = row[n_edges - 1]; hi = n_nodes;  }
    else {
        lo = row[e - 1];
        hi = row[e];
        if (lo == hi) return;
    }
    for (int r = lo + 1; r <= hi; ++r) ptr[r] = e;
}

// ---------------------------------------------------------------------------
// Kernel 3: out[r,:] = sum_e val[e] * y[col[e],:]   (bf16 gather, fp32 acc)
// TWO rows per wave (half=lane>>5, hl=lane&31), lane owns uint2 (4 cols).
// 8-edge batches. Deep pipeline via strict vmcnt-FIFO issue order:
//   per iter:  cv(b+2) ; G(b+1) ; consume(b)
// so every wait is a NON-DRAINING vmcnt(12): 8 gathers (4 KB/wave) + 4 cv
// loads stay in flight permanently. cv kept in VGPRs (c double-buffered,
// v triple-buffered, U double-buffered) -> 6-unrolled rotation, no SGPR
// blowup, no readfirstlane. vals pre-masked at load.
// ---------------------------------------------------------------------------
__global__ __launch_bounds__(256) void spmm_kernel(
    const uint2* __restrict__ yb2, const int* __restrict__ ptr,
    const int* __restrict__ col, const float* __restrict__ val,
    float4* __restrict__ out4, int n_nodes, int n_edges)
{
    const int gid  = blockIdx.x * blockDim.x + threadIdx.x;
    const int w    = gid >> 6;
    const int lane = threadIdx.x & 63;
    const int half = lane >> 5;
    const int hl   = lane & 31;
    const int row  = (w << 1) + half;
    const bool valid = (row < n_nodes);

    int s = 0, e = 0;
    if (valid) { s = ptr[row]; e = ptr[row + 1]; }

    const int base = s & ~7;                   // 32B-aligned 8-edge batches
    const int nb   = valid ? ((e - base + 7) >> 3) : 0;

    f32x2 a0 = {0.f, 0.f}, a1 = {0.f, 0.f};

    // cv slots: c x2 (int4 pairs), v x3 (float4 pairs); U x2 (8 x uint2)
    int4   cL[2], cH[2];
    float4 vL[3], vH[3];
    uint2  U0[8], U1[8];

#define CVLOAD(b_, ci_, vi_)                                                 \
    if ((b_) < nb) {                                                         \
        const int o_ = base + ((b_) << 3);                                   \
        if (o_ + 8 <= n_edges) {                                             \
            cL[ci_] = *reinterpret_cast<const int4*>(col + o_);              \
            cH[ci_] = *reinterpret_cast<const int4*>(col + o_ + 4);          \
            vL[vi_] = *reinterpret_cast<const float4*>(val + o_);            \
            vH[vi_] = *reinterpret_cast<const float4*>(val + o_ + 4);        \
        } else {                                                             \
            const int m_ = n_edges - 1;                                      \
            cL[ci_].x = col[min(o_ + 0, m_)]; cL[ci_].y = col[min(o_ + 1, m_)]; \
            cL[ci_].z = col[min(o_ + 2, m_)]; cL[ci_].w = col[min(o_ + 3, m_)]; \
            cH[ci_].x = col[min(o_ + 4, m_)]; cH[ci_].y = col[min(o_ + 5, m_)]; \
            cH[ci_].z = col[min(o_ + 6, m_)]; cH[ci_].w = col[min(o_ + 7, m_)]; \
            vL[vi_].x = val[min(o_ + 0, m_)]; vL[vi_].y = val[min(o_ + 1, m_)]; \
            vL[vi_].z = val[min(o_ + 2, m_)]; vL[vi_].w = val[min(o_ + 3, m_)]; \
            vH[vi_].x = val[min(o_ + 4, m_)]; vH[vi_].y = val[min(o_ + 5, m_)]; \
            vH[vi_].z = val[min(o_ + 6, m_)]; vH[vi_].w = val[min(o_ + 7, m_)]; \
        }                                                                    \
        vL[vi_].x = (o_ + 0 >= s && o_ + 0 < e) ? vL[vi_].x : 0.f;           \
        vL[vi_].y = (o_ + 1 >= s && o_ + 1 < e) ? vL[vi_].y : 0.f;           \
        vL[vi_].z = (o_ + 2 >= s && o_ + 2 < e) ? vL[vi_].z : 0.f;           \
        vL[vi_].w = (o_ + 3 >= s && o_ + 3 < e) ? vL[vi_].w : 0.f;           \
        vH[vi_].x = (o_ + 4 >= s && o_ + 4 < e) ? vH[vi_].x : 0.f;           \
        vH[vi_].y = (o_ + 5 >= s && o_ + 5 < e) ? vH[vi_].y : 0.f;           \
        vH[vi_].z = (o_ + 6 >= s && o_ + 6 < e) ? vH[vi_].z : 0.f;           \
        vH[vi_].w = (o_ + 7 >= s && o_ + 7 < e) ? vH[vi_].w : 0.f;           \
    }

#define GATHER(b_, ci_, U_)                                                  \
    if ((b_) < nb) {                                                         \
        U_[0] = yb2[(size_t)cL[ci_].x * 32 + hl];                            \
        U_[1] = yb2[(size_t)cL[ci_].y * 32 + hl];                            \
        U_[2] = yb2[(size_t)cL[ci_].z * 32 + hl];                            \
        U_[3] = yb2[(size_t)cL[ci_].w * 32 + hl];                            \
        U_[4] = yb2[(size_t)cH[ci_].x * 32 + hl];                            \
        U_[5] = yb2[(size_t)cH[ci_].y * 32 + hl];                            \
        U_[6] = yb2[(size_t)cH[ci_].z * 32 + hl];                            \
        U_[7] = yb2[(size_t)cH[ci_].w * 32 + hl];                            \
    }

#define FMA1(u_, v_)                                                         \
    {                                                                        \
        f32x2 t_, vv_;                                                       \
        vv_.x = (v_); vv_.y = (v_);                                          \
        t_.x = bflo((u_).x); t_.y = bfhi((u_).x); a0 += vv_ * t_;            \
        t_.x = bflo((u_).y); t_.y = bfhi((u_).y); a1 += vv_ * t_;            \
    }
#define CONSUME(b_, vi_, U_)                                                 \
    if ((b_) < nb) {                                                         \
        FMA1(U_[0], vL[vi_].x); FMA1(U_[1], vL[vi_].y);                      \
        FMA1(U_[2], vL[vi_].z); FMA1(U_[3], vL[vi_].w);                      \
        FMA1(U_[4], vH[vi_].x); FMA1(U_[5], vH[vi_].y);                      \
        FMA1(U_[6], vH[vi_].z); FMA1(U_[7], vH[vi_].w);                      \
    }

    // iter(b): cvload(b+2 -> c[b%2], v[(b+2)%3]); gather(b+1, c[(b+1)%2] -> U[(b+1)%2]); consume(b, v[b%3], U[b%2])
#define ITER(b_, CI2_, VI2_, CI1_, UI1_, VI0_, UI0_)                         \
    {                                                                        \
        CVLOAD((b_) + 2, CI2_, VI2_);                                        \
        GATHER((b_) + 1, CI1_, UI1_);                                        \
        CONSUME((b_), VI0_, UI0_);                                           \
    }

    if (nb > 0) {
        CVLOAD(0, 0, 0);
        CVLOAD(1, 1, 1);
        GATHER(0, 0, U0);

        for (int b = 0; b < nb; b += 6) {
            ITER(b + 0, 0, 2, 1, U1, 0, U0);
            ITER(b + 1, 1, 0, 0, U0, 1, U1);
            ITER(b + 2, 0, 1, 1, U1, 2, U0);
            ITER(b + 3, 1, 2, 0, U0, 0, U1);
            ITER(b + 4, 0, 0, 1, U1, 1, U0);
            ITER(b + 5, 1, 1, 0, U0, 2, U1);
        }
    }
#undef CVLOAD
#undef GATHER
#undef FMA1
#undef CONSUME
#undef ITER

    if (valid) {
        f32x4 o;
        o.x = a0.x; o.y = a0.y; o.z = a1.x; o.w = a1.y;
        __builtin_nontemporal_store(o,
            reinterpret_cast<f32x4*>(out4 + (size_t)row * 32 + hl));
    }
}

// ---------------------------------------------------------------------------
extern "C" void kernel_launch(void* const* d_in, const int* in_sizes, int n_in,
                              void* d_out, int out_size, void* d_ws, size_t ws_size,
                              hipStream_t stream)
{
    const float* x        = (const float*)d_in[0];
    const int*   edge_row = (const int*)  d_in[1];
    const int*   edge_col = (const int*)  d_in[2];
    const float* edge_val = (const float*)d_in[3];
    const float* W        = (const float*)d_in[4];
    float*       out      = (float*)d_out;

    const int n_nodes = in_sizes[0] / D;
    const int n_edges = in_sizes[1];
    const int ntiles  = (n_nodes + 15) / 16;

    // workspace layout: y_bf16 [n_nodes*D2U uint] | row_ptr [(n_nodes+1) i32]
    unsigned* y   = (unsigned*)d_ws;
    int*      ptr = (int*)((char*)d_ws + (size_t)n_nodes * D2U * sizeof(unsigned));

    // 1) y = bf16(x @ W)  (MFMA)
    gemm_mfma_kernel<<<512, 256, 0, stream>>>(x, W, y, n_nodes, ntiles);

    // 2) row_ptr
    {
        int blocks = (n_edges + 1 + 255) / 256;
        build_rowptr_kernel<<<blocks, 256, 0, stream>>>(edge_row, ptr, n_edges, n_nodes);
    }
    // 3) out = A @ y   (two rows per wave, deep-pipelined)
    {
        int nwaves = (n_nodes + 1) / 2;
        int blocks = (nwaves + 3) / 4;          // 4 waves per 256-thread block
        spmm_kernel<<<blocks, 256, 0, stream>>>((const uint2*)y, ptr,
                                                edge_col, edge_val,
                                                (float4*)out, n_nodes, n_edges);
    }
}

// Round 11
// 143.457 us; speedup vs baseline: 3.8579x; 1.1372x over previous
//
#include <hip/hip_runtime.h>
#include <hip/hip_bf16.h>

#define D 128            // D_IN == D_OUT
#define D2U 64           // D/2 packed bf16 pairs (uint) per row

typedef __attribute__((ext_vector_type(8))) short  short8;
typedef __attribute__((ext_vector_type(4))) float  f32x4;
typedef __attribute__((ext_vector_type(2))) float  f32x2;

// fp32 -> bf16 (RTNE)
__device__ __forceinline__ unsigned f2bf(float f) {
    unsigned u = __float_as_uint(f);
    u += 0x7FFFu + ((u >> 16) & 1u);
    return u >> 16;
}
__device__ __forceinline__ unsigned pk2(float a, float b) {
    return f2bf(a) | (f2bf(b) << 16);
}
__device__ __forceinline__ float bflo(unsigned u) { return __uint_as_float(u << 16); }
__device__ __forceinline__ float bfhi(unsigned u) { return __uint_as_float(u & 0xFFFF0000u); }

// ---------------------------------------------------------------------------
// Kernel 1: y = bf16(x @ W) via MFMA 16x16x32 bf16, row-major y.
// (R4-proven: W^T swizzled in LDS -> 128 VGPRs of fragments; x streamed
// direct-from-global, double-buffered; lane owns 4 consecutive cols of a row.)
// ---------------------------------------------------------------------------
__global__ __launch_bounds__(256, 2) void gemm_mfma_kernel(
    const float* __restrict__ x, const float* __restrict__ W,
    unsigned* __restrict__ y, int n_nodes, int ntiles)
{
    __shared__ unsigned short Wt[D * D];   // bf16 [c][k], k XOR-swizzled, 32 KB

    const int t = threadIdx.x;

    {
        const float4* W4 = reinterpret_cast<const float4*>(W);
#pragma unroll
        for (int m = 0; m < 16; ++m) {
            const int idx4 = m * 256 + t;        // float4 index
            const int k  = idx4 >> 5;            // 32 float4 per k-row
            const int c0 = (idx4 & 31) << 2;
            const float4 w = W4[idx4];
            const float wv[4] = {w.x, w.y, w.z, w.w};
#pragma unroll
            for (int i = 0; i < 4; ++i) {
                const int c    = c0 + i;
                const int slot = (k >> 3) ^ (c & 15);
                Wt[c * 128 + slot * 8 + (k & 7)] = (unsigned short)f2bf(wv[i]);
            }
        }
    }
    __syncthreads();

    const int lane = t & 63;
    const int cl   = lane & 15;
    const int g    = lane >> 4;

    short8 wf[8][4];
#pragma unroll
    for (int ct = 0; ct < 8; ++ct)
#pragma unroll
        for (int ks = 0; ks < 4; ++ks) {
            const int c    = ct * 16 + cl;
            const int slot = (ks * 4 + g) ^ cl;
            wf[ct][ks] = *reinterpret_cast<const short8*>(&Wt[c * 128 + slot * 8]);
        }

    const int wave   = (blockIdx.x << 2) | (t >> 6);
    const int nwaves = gridDim.x << 2;

#define LOADX(rt_, buf_)                                                      \
    {                                                                         \
        int r_ = (rt_) * 16 + cl;                                             \
        if (r_ >= n_nodes) r_ = n_nodes - 1;                                  \
        const float* p_ = x + (size_t)r_ * D + g * 8;                         \
        _Pragma("unroll")                                                     \
        for (int ks_ = 0; ks_ < 4; ++ks_) {                                   \
            buf_[2 * ks_]     = *reinterpret_cast<const float4*>(p_ + ks_ * 32);     \
            buf_[2 * ks_ + 1] = *reinterpret_cast<const float4*>(p_ + ks_ * 32 + 4); \
        }                                                                     \
    }

#define COMPUTE(rt_, buf_)                                                    \
    {                                                                         \
        f32x4 acc_[8];                                                        \
        _Pragma("unroll")                                                     \
        for (int ct_ = 0; ct_ < 8; ++ct_) acc_[ct_] = (f32x4)(0.f);           \
        _Pragma("unroll")                                                     \
        for (int ks_ = 0; ks_ < 4; ++ks_) {                                   \
            short8 xf_;                                                       \
            unsigned* xu_ = reinterpret_cast<unsigned*>(&xf_);                \
            const float4 a_ = buf_[2 * ks_], b_ = buf_[2 * ks_ + 1];          \
            xu_[0] = pk2(a_.x, a_.y); xu_[1] = pk2(a_.z, a_.w);               \
            xu_[2] = pk2(b_.x, b_.y); xu_[3] = pk2(b_.z, b_.w);               \
            _Pragma("unroll")                                                 \
            for (int ct_ = 0; ct_ < 8; ++ct_)                                 \
                acc_[ct_] = __builtin_amdgcn_mfma_f32_16x16x32_bf16(          \
                    wf[ct_][ks_], xf_, acc_[ct_], 0, 0, 0);                   \
        }                                                                     \
        const int r_ = (rt_) * 16 + cl;                                       \
        if (r_ < n_nodes) {                                                   \
            unsigned* yp_ = y + (size_t)r_ * D2U + g * 2;                     \
            _Pragma("unroll")                                                 \
            for (int ct_ = 0; ct_ < 8; ++ct_) {                               \
                uint2 v2_ = make_uint2(pk2(acc_[ct_][0], acc_[ct_][1]),       \
                                       pk2(acc_[ct_][2], acc_[ct_][3]));      \
                *reinterpret_cast<uint2*>(yp_ + ct_ * 8) = v2_;               \
            }                                                                 \
        }                                                                     \
    }

    int rt = wave;
    if (rt >= ntiles) return;
    float4 bufA[8], bufB[8];
    LOADX(rt, bufA);
    while (true) {
        int nxt = rt + nwaves;
        if (nxt < ntiles) {
            LOADX(nxt, bufB);
            COMPUTE(rt, bufA);
            rt = nxt;
            nxt = rt + nwaves;
            if (nxt < ntiles) {
                LOADX(nxt, bufA);
                COMPUTE(rt, bufB);
                rt = nxt;
            } else { COMPUTE(rt, bufB); break; }
        } else { COMPUTE(rt, bufA); break; }
    }
#undef LOADX
#undef COMPUTE
}

// ---------------------------------------------------------------------------
// Kernel 2: build CSR row_ptr from sorted edge_row.
// ---------------------------------------------------------------------------
__global__ __launch_bounds__(256) void build_rowptr_kernel(
    const int* __restrict__ row, int* __restrict__ ptr, int n_edges, int n_nodes)
{
    int e = blockIdx.x * blockDim.x + threadIdx.x;
    if (e > n_edges) return;
    int lo, hi;                     // set ptr[r] = e for r in (lo, hi]
    if (e == 0)            { lo = -1;               hi = row[0];   }
    else if (e == n_edges) { lo = row[n_edges - 1]; hi = n_nodes;  }
    else {
        lo = row[e - 1];
        hi = row[e];
        if (lo == hi) return;
    }
    for (int r = lo + 1; r <= hi; ++r) ptr[r] = e;
}

// ---------------------------------------------------------------------------
// Kernel 3 (R3-proven, 111.2 µs measured): one wave per row, lane owns one
// packed uint (2 cols). 16-edge batches; cv scalarized via readfirstlane'd
// row bounds (s_load on lgkmcnt, separate from the gather vmcnt FIFO);
// next batch's cv prefetched before consume; 16 independent gathers per
// batch amortize the per-batch drain. Only change vs R3: NT out store.
// ---------------------------------------------------------------------------
#define EUNR 16

__global__ __launch_bounds__(256) void spmm_kernel(
    const unsigned* __restrict__ yb, const int* __restrict__ ptr,
    const int* __restrict__ col, const float* __restrict__ val,
    float2* __restrict__ out2, int n_nodes)
{
    int gid  = blockIdx.x * blockDim.x + threadIdx.x;
    int r    = gid >> 6;            // one wave per row (uniform across wave)
    int lane = threadIdx.x & 63;
    if (r >= n_nodes) return;

    const int s = __builtin_amdgcn_readfirstlane(ptr[r]);
    const int e = __builtin_amdgcn_readfirstlane(ptr[r + 1]);

    float ax = 0.f, ay = 0.f;
    int i = s;

    if (i + EUNR <= e) {
        int   c[EUNR];
        float v[EUNR];
#pragma unroll
        for (int k = 0; k < EUNR; ++k) { c[k] = col[i + k]; v[k] = val[i + k]; }

        while (true) {
            unsigned u[EUNR];
#pragma unroll
            for (int k = 0; k < EUNR; ++k)
                u[k] = yb[(size_t)c[k] * D2U + lane];

            const int  ni   = i + EUNR;
            const bool more = (ni + EUNR <= e);

            int   nc[EUNR];
            float nv[EUNR];
            if (more) {
#pragma unroll
                for (int k = 0; k < EUNR; ++k) { nc[k] = col[ni + k]; nv[k] = val[ni + k]; }
            }

#pragma unroll
            for (int k = 0; k < EUNR; ++k) {
                ax += v[k] * bflo(u[k]);
                ay += v[k] * bfhi(u[k]);
            }

            i = ni;
            if (!more) break;
#pragma unroll
            for (int k = 0; k < EUNR; ++k) { c[k] = nc[k]; v[k] = nv[k]; }
        }
    }

    // tail: 4-unrolled then scalar
    for (; i + 4 <= e; i += 4) {
        const int   c0 = col[i],     c1 = col[i + 1], c2 = col[i + 2], c3 = col[i + 3];
        const float v0 = val[i],     v1 = val[i + 1], v2 = val[i + 2], v3 = val[i + 3];
        const unsigned u0 = yb[(size_t)c0 * D2U + lane];
        const unsigned u1 = yb[(size_t)c1 * D2U + lane];
        const unsigned u2 = yb[(size_t)c2 * D2U + lane];
        const unsigned u3 = yb[(size_t)c3 * D2U + lane];
        ax += v0 * bflo(u0); ay += v0 * bfhi(u0);
        ax += v1 * bflo(u1); ay += v1 * bfhi(u1);
        ax += v2 * bflo(u2); ay += v2 * bfhi(u2);
        ax += v3 * bflo(u3); ay += v3 * bfhi(u3);
    }
    for (; i < e; ++i) {
        const int      c = col[i];
        const float    v = val[i];
        const unsigned u = yb[(size_t)c * D2U + lane];
        ax += v * bflo(u); ay += v * bfhi(u);
    }

    f32x2 o;
    o.x = ax; o.y = ay;
    __builtin_nontemporal_store(o,
        reinterpret_cast<f32x2*>(out2 + (size_t)r * D2U + lane));
}

// ---------------------------------------------------------------------------
extern "C" void kernel_launch(void* const* d_in, const int* in_sizes, int n_in,
                              void* d_out, int out_size, void* d_ws, size_t ws_size,
                              hipStream_t stream)
{
    const float* x        = (const float*)d_in[0];
    const int*   edge_row = (const int*)  d_in[1];
    const int*   edge_col = (const int*)  d_in[2];
    const float* edge_val = (const float*)d_in[3];
    const float* W        = (const float*)d_in[4];
    float*       out      = (float*)d_out;

    const int n_nodes = in_sizes[0] / D;
    const int n_edges = in_sizes[1];
    const int ntiles  = (n_nodes + 15) / 16;

    // workspace layout: y_bf16 [n_nodes*D2U uint] | row_ptr [(n_nodes+1) i32]
    unsigned* y   = (unsigned*)d_ws;
    int*      ptr = (int*)((char*)d_ws + (size_t)n_nodes * D2U * sizeof(unsigned));

    // 1) y = bf16(x @ W)  (MFMA)
    gemm_mfma_kernel<<<512, 256, 0, stream>>>(x, W, y, n_nodes, ntiles);

    // 2) row_ptr
    {
        int blocks = (n_edges + 1 + 255) / 256;
        build_rowptr_kernel<<<blocks, 256, 0, stream>>>(edge_row, ptr, n_edges, n_nodes);
    }
    // 3) out = A @ y   (one wave per row, 16-deep batches)
    {
        int rows_per_block = 256 / 64;
        int blocks = (n_nodes + rows_per_block - 1) / rows_per_block;
        spmm_kernel<<<blocks, 256, 0, stream>>>(y, ptr, edge_col, edge_val,
                                                (float2*)out, n_nodes);
    }
}